// Round 3
// baseline (772.483 us; speedup 1.0000x reference)
//
#include <hip/hip_runtime.h>
#include <hip/hip_bf16.h>

#define N_NODES 100000
#define IN_F 128
#define OUT_F 64
#define BROWS 128                 // rows per bucket
#define NB 782                    // ceil(100000/128)
#define BIN_TILE 2048             // edges per bin tile (8 per thread)

// ===========================================================================
// Kernel 1: support = input @ W    [N,128] x [128,64] -> [N,64]
// (unchanged from round 2 — lane = row, A in LDS [64][129], scalar W loads)
// ===========================================================================
__global__ __launch_bounds__(256) void gemm_kernel(
    const float* __restrict__ in, const float* __restrict__ W,
    float* __restrict__ support)
{
    __shared__ float Alds[64 * 129];
    const int t = threadIdx.x;
    const long row0 = (long)blockIdx.x * 64;

    #pragma unroll
    for (int i = 0; i < 8; ++i) {
        int fi = t + i * 256;
        int r  = fi >> 5;
        int k4 = (fi & 31) << 2;
        float4 v = make_float4(0.f, 0.f, 0.f, 0.f);
        if (row0 + r < N_NODES)
            v = *(const float4*)(in + (row0 + r) * IN_F + k4);
        Alds[r * 129 + k4 + 0] = v.x;
        Alds[r * 129 + k4 + 1] = v.y;
        Alds[r * 129 + k4 + 2] = v.z;
        Alds[r * 129 + k4 + 3] = v.w;
    }
    __syncthreads();

    const int lane = t & 63;
    const int c0   = __builtin_amdgcn_readfirstlane((t >> 6) << 4);
    const float* __restrict__ Wp = W + c0;

    float acc[16];
    #pragma unroll
    for (int i = 0; i < 16; ++i) acc[i] = 0.f;

    const float* Ar = Alds + lane * 129;
    for (int k = 0; k < IN_F; ++k) {
        const float a = Ar[k];
        const float4 w0 = *(const float4*)(Wp + k * OUT_F + 0);
        const float4 w1 = *(const float4*)(Wp + k * OUT_F + 4);
        const float4 w2 = *(const float4*)(Wp + k * OUT_F + 8);
        const float4 w3 = *(const float4*)(Wp + k * OUT_F + 12);
        acc[0]  = fmaf(a, w0.x, acc[0]);  acc[1]  = fmaf(a, w0.y, acc[1]);
        acc[2]  = fmaf(a, w0.z, acc[2]);  acc[3]  = fmaf(a, w0.w, acc[3]);
        acc[4]  = fmaf(a, w1.x, acc[4]);  acc[5]  = fmaf(a, w1.y, acc[5]);
        acc[6]  = fmaf(a, w1.z, acc[6]);  acc[7]  = fmaf(a, w1.w, acc[7]);
        acc[8]  = fmaf(a, w2.x, acc[8]);  acc[9]  = fmaf(a, w2.y, acc[9]);
        acc[10] = fmaf(a, w2.z, acc[10]); acc[11] = fmaf(a, w2.w, acc[11]);
        acc[12] = fmaf(a, w3.x, acc[12]); acc[13] = fmaf(a, w3.y, acc[13]);
        acc[14] = fmaf(a, w3.z, acc[14]); acc[15] = fmaf(a, w3.w, acc[15]);
    }

    const long orow = row0 + lane;
    if (orow < N_NODES) {
        float* o = support + orow * OUT_F + c0;
        *(float4*)(o + 0)  = make_float4(acc[0],  acc[1],  acc[2],  acc[3]);
        *(float4*)(o + 4)  = make_float4(acc[4],  acc[5],  acc[6],  acc[7]);
        *(float4*)(o + 8)  = make_float4(acc[8],  acc[9],  acc[10], acc[11]);
        *(float4*)(o + 12) = make_float4(acc[12], acc[13], acc[14], acc[15]);
    }
}

// ===========================================================================
// zero a small int array
// ===========================================================================
__global__ __launch_bounds__(256) void zero_kernel(int* __restrict__ p, int n)
{
    int i = blockIdx.x * 256 + threadIdx.x;
    if (i < n) p[i] = 0;
}

// ===========================================================================
// B1: per-bucket edge counts (LDS-aggregated histogram -> global add)
// ===========================================================================
__global__ __launch_bounds__(256) void count_kernel(
    const int* __restrict__ rows, int* __restrict__ cnt, int nE)
{
    __shared__ int hist[NB];
    const int t = threadIdx.x;
    for (int i = t; i < NB; i += 256) hist[i] = 0;
    __syncthreads();

    for (int e = blockIdx.x * 256 + t; e < nE; e += gridDim.x * 256)
        atomicAdd(&hist[rows[e] >> 7], 1);
    __syncthreads();

    for (int i = t; i < NB; i += 256) {
        int h = hist[i];
        if (h) atomicAdd(&cnt[i], h);
    }
}

// ===========================================================================
// B2: exclusive scan of NB counts (single block). base <- scan(cnt),
// cursor <- same, base[NB] = nE.
// ===========================================================================
__global__ __launch_bounds__(256) void scan_kernel(
    const int* __restrict__ cnt, int* __restrict__ base,
    int* __restrict__ cursor, int nE)
{
    __shared__ int lds[256];
    const int t = threadIdx.x;
    const int i0 = t * 4;
    int c0 = (i0 + 0 < NB) ? cnt[i0 + 0] : 0;
    int c1 = (i0 + 1 < NB) ? cnt[i0 + 1] : 0;
    int c2 = (i0 + 2 < NB) ? cnt[i0 + 2] : 0;
    int c3 = (i0 + 3 < NB) ? cnt[i0 + 3] : 0;
    const int tot = c0 + c1 + c2 + c3;

    lds[t] = tot;
    __syncthreads();
    int sum = tot;
    #pragma unroll
    for (int off = 1; off < 256; off <<= 1) {
        int y = (t >= off) ? lds[t - off] : 0;
        __syncthreads();
        sum += y;
        lds[t] = sum;
        __syncthreads();
    }
    const int excl = sum - tot;

    if (i0 + 0 < NB) { base[i0 + 0] = excl;                cursor[i0 + 0] = excl; }
    if (i0 + 1 < NB) { base[i0 + 1] = excl + c0;           cursor[i0 + 1] = excl + c0; }
    if (i0 + 2 < NB) { base[i0 + 2] = excl + c0 + c1;      cursor[i0 + 2] = excl + c0 + c1; }
    if (i0 + 3 < NB) { base[i0 + 3] = excl + c0 + c1 + c2; cursor[i0 + 3] = excl + c0 + c1 + c2; }
    if (t == 0) base[NB] = nE;
}

// ===========================================================================
// B3: bin edges into bucket-grouped array. Per tile: LDS hist gives each
// item a local rank; one global cursor atomic per (tile,bucket); writes
// cluster around the NB live cursor fronts (L2-resident, ~full lines).
// payload: x = (row&127)<<17 | col (col<2^17), y = bits of val.
// ===========================================================================
__global__ __launch_bounds__(256) void bin_kernel(
    const int* __restrict__ rows, const int* __restrict__ cols,
    const float* __restrict__ vals, int* __restrict__ cursor,
    uint2* __restrict__ binned, int nE)
{
    __shared__ int hist[NB];
    __shared__ int lbase[NB];
    const int t  = threadIdx.x;
    const int tb = blockIdx.x * BIN_TILE;

    for (int i = t; i < NB; i += 256) hist[i] = 0;
    __syncthreads();

    int myr[8], myrank[8];
    #pragma unroll
    for (int i = 0; i < 8; ++i) {
        int e = tb + i * 256 + t;
        if (e < nE) {
            int r = rows[e];
            myr[i] = r;
            myrank[i] = atomicAdd(&hist[r >> 7], 1);
        } else myr[i] = -1;
    }
    __syncthreads();

    for (int i = t; i < NB; i += 256) {
        int h = hist[i];
        lbase[i] = h ? atomicAdd(&cursor[i], h) : 0;
    }
    __syncthreads();

    #pragma unroll
    for (int i = 0; i < 8; ++i) {
        int e = tb + i * 256 + t;
        if (e < nE) {
            int r = myr[i];
            unsigned pack = ((unsigned)(r & (BROWS - 1)) << 17) | (unsigned)cols[e];
            binned[lbase[r >> 7] + myrank[i]] =
                make_uint2(pack, __float_as_uint(vals[e]));
        }
    }
}

// ===========================================================================
// B4: per-bucket accumulate. One block per bucket; acc[128][64] fp32 in LDS.
// lane = feature; per edge: 256B coalesced gather of support row + ds_add_f32
// (2 lanes/bank = free). Bias fused into the single coalesced output write.
// ===========================================================================
#define UN 8
__global__ __launch_bounds__(256) void bucket_spmm(
    const int* __restrict__ base, const uint2* __restrict__ binned,
    const float* __restrict__ support, const float* __restrict__ bias,
    float* __restrict__ out)
{
    __shared__ float acc[BROWS * OUT_F];   // 32 KB
    const int t = threadIdx.x;
    float4* acc4 = (float4*)acc;
    #pragma unroll
    for (int i = 0; i < 8; ++i)
        acc4[t + i * 256] = make_float4(0.f, 0.f, 0.f, 0.f);
    __syncthreads();

    const int b = blockIdx.x;
    const int s = base[b];
    const int e = base[b + 1];
    const int wid  = __builtin_amdgcn_readfirstlane(t >> 6);
    const int lane = t & 63;

    for (int j = s + wid * UN; j < e; j += 4 * UN) {
        float g[UN], v[UN];
        int rl[UN];
        #pragma unroll
        for (int k = 0; k < UN; ++k) {
            int idx = j + k;
            uint2 p = (idx < e) ? binned[idx] : make_uint2(0u, 0u);
            int col = (int)(p.x & 131071u);
            rl[k] = (int)(p.x >> 17);
            v[k]  = __uint_as_float(p.y);
            g[k]  = support[(long)col * OUT_F + lane];
        }
        #pragma unroll
        for (int k = 0; k < UN; ++k)
            atomicAdd(&acc[rl[k] * OUT_F + lane], v[k] * g[k]);
    }
    __syncthreads();

    // epilogue: out[bucket rows] = acc + bias (coalesced float4)
    const int row0  = b * BROWS;
    const int nrows = min(BROWS, N_NODES - row0);
    const int nf4   = nrows * 16;
    const float4 bb = ((const float4*)bias)[t & 15];
    float4* out4 = (float4*)(out + (long)row0 * OUT_F);
    for (int i = t; i < nf4; i += 256) {
        float4 a = acc4[i];
        out4[i] = make_float4(a.x + bb.x, a.y + bb.y, a.z + bb.z, a.w + bb.w);
    }
}

// ===========================================================================
// Fallback path (ws too small): bias-init + atomic scatter
// ===========================================================================
__global__ __launch_bounds__(256) void bias_init_kernel(
    float* __restrict__ out, const float* __restrict__ bias, int total4)
{
    const float4* b4 = (const float4*)bias;
    float4* o4 = (float4*)out;
    int i = blockIdx.x * blockDim.x + threadIdx.x;
    int stride = gridDim.x * blockDim.x;
    for (; i < total4; i += stride)
        o4[i] = b4[i & 15];
}

__global__ __launch_bounds__(256) void scatter_kernel(
    const float* __restrict__ vals, const int* __restrict__ rows,
    const int* __restrict__ cols, const float* __restrict__ support,
    float* __restrict__ out, int nE)
{
    const int e = blockIdx.x * 4 + (threadIdx.x >> 6);
    if (e >= nE) return;
    const int f = threadIdx.x & 63;
    const float m = vals[e] * support[(long)cols[e] * OUT_F + f];
    atomicAdd(&out[(long)rows[e] * OUT_F + f], m);
}

// ===========================================================================
extern "C" void kernel_launch(void* const* d_in, const int* in_sizes, int n_in,
                              void* d_out, int out_size, void* d_ws, size_t ws_size,
                              hipStream_t stream) {
    const float* input    = (const float*)d_in[0];
    const float* weights  = (const float*)d_in[1];
    const float* bias     = (const float*)d_in[2];
    const float* adj_vals = (const float*)d_in[3];
    const int*   adj_rows = (const int*)d_in[4];
    const int*   adj_cols = (const int*)d_in[5];
    const int nE = in_sizes[3];

    float* out = (float*)d_out;

    // workspace layout (16B-aligned offsets)
    char* ws = (char*)d_ws;
    const size_t off_support = 0;                      // N*64 floats = 25.6 MB
    const size_t off_base    = 25600000;               // (NB+1) ints
    const size_t off_cursor  = off_base + 3200;        // NB ints
    const size_t off_binned  = off_cursor + 3200;      // nE uint2
    const size_t required    = off_binned + (size_t)nE * 8;

    float* support = (float*)(ws + off_support);
    int*   bbase   = (int*)  (ws + off_base);
    int*   cursor  = (int*)  (ws + off_cursor);
    uint2* binned  = (uint2*)(ws + off_binned);

    // 1) support = input @ W
    hipLaunchKernelGGL(gemm_kernel, dim3((N_NODES + 63) / 64), dim3(256), 0,
                       stream, input, weights, support);

    if (ws_size >= required) {
        // 2) cursor (as counts) = 0
        hipLaunchKernelGGL(zero_kernel, dim3((NB + 255) / 256), dim3(256),
                           0, stream, cursor, NB);
        // 3) per-bucket counts
        hipLaunchKernelGGL(count_kernel, dim3(256), dim3(256), 0, stream,
                           adj_rows, cursor, nE);
        // 4) scan -> base, cursor
        hipLaunchKernelGGL(scan_kernel, dim3(1), dim3(256), 0, stream,
                           cursor, bbase, cursor, nE);
        // 5) bin edges by bucket
        hipLaunchKernelGGL(bin_kernel, dim3((nE + BIN_TILE - 1) / BIN_TILE),
                           dim3(256), 0, stream,
                           adj_rows, adj_cols, adj_vals, cursor, binned, nE);
        // 6) per-bucket LDS accumulate + bias -> out
        hipLaunchKernelGGL(bucket_spmm, dim3(NB), dim3(256), 0, stream,
                           bbase, binned, support, bias, out);
    } else {
        hipLaunchKernelGGL(bias_init_kernel, dim3(2048), dim3(256), 0, stream,
                           out, bias, N_NODES * OUT_F / 4);
        hipLaunchKernelGGL(scatter_kernel, dim3((nE + 3) / 4), dim3(256),
                           0, stream, adj_vals, adj_rows, adj_cols, support,
                           out, nE);
    }
}

// Round 4
// 695.506 us; speedup vs baseline: 1.1107x; 1.1107x over previous
//
#include <hip/hip_runtime.h>
#include <hip/hip_bf16.h>

#define N_NODES 100000
#define IN_F 128
#define OUT_F 64
#define BROWS 64                  // rows per bucket
#define NB 1563                   // ceil(100000/64)
#define BIN_TILE 2048             // edges per bin tile (8 per thread)
#define UN 8                      // edges per wave per iteration in spmm

// ===========================================================================
// Kernel 1: support = input @ W    [N,128] x [128,64] -> [N,64]
// lane = row, A in LDS [64][129], wave-uniform W loads (scalar path)
// ===========================================================================
__global__ __launch_bounds__(256) void gemm_kernel(
    const float* __restrict__ in, const float* __restrict__ W,
    float* __restrict__ support)
{
    __shared__ float Alds[64 * 129];
    const int t = threadIdx.x;
    const long row0 = (long)blockIdx.x * 64;

    #pragma unroll
    for (int i = 0; i < 8; ++i) {
        int fi = t + i * 256;
        int r  = fi >> 5;
        int k4 = (fi & 31) << 2;
        float4 v = make_float4(0.f, 0.f, 0.f, 0.f);
        if (row0 + r < N_NODES)
            v = *(const float4*)(in + (row0 + r) * IN_F + k4);
        Alds[r * 129 + k4 + 0] = v.x;
        Alds[r * 129 + k4 + 1] = v.y;
        Alds[r * 129 + k4 + 2] = v.z;
        Alds[r * 129 + k4 + 3] = v.w;
    }
    __syncthreads();

    const int lane = t & 63;
    const int c0   = __builtin_amdgcn_readfirstlane((t >> 6) << 4);
    const float* __restrict__ Wp = W + c0;

    float acc[16];
    #pragma unroll
    for (int i = 0; i < 16; ++i) acc[i] = 0.f;

    const float* Ar = Alds + lane * 129;
    for (int k = 0; k < IN_F; ++k) {
        const float a = Ar[k];
        const float4 w0 = *(const float4*)(Wp + k * OUT_F + 0);
        const float4 w1 = *(const float4*)(Wp + k * OUT_F + 4);
        const float4 w2 = *(const float4*)(Wp + k * OUT_F + 8);
        const float4 w3 = *(const float4*)(Wp + k * OUT_F + 12);
        acc[0]  = fmaf(a, w0.x, acc[0]);  acc[1]  = fmaf(a, w0.y, acc[1]);
        acc[2]  = fmaf(a, w0.z, acc[2]);  acc[3]  = fmaf(a, w0.w, acc[3]);
        acc[4]  = fmaf(a, w1.x, acc[4]);  acc[5]  = fmaf(a, w1.y, acc[5]);
        acc[6]  = fmaf(a, w1.z, acc[6]);  acc[7]  = fmaf(a, w1.w, acc[7]);
        acc[8]  = fmaf(a, w2.x, acc[8]);  acc[9]  = fmaf(a, w2.y, acc[9]);
        acc[10] = fmaf(a, w2.z, acc[10]); acc[11] = fmaf(a, w2.w, acc[11]);
        acc[12] = fmaf(a, w3.x, acc[12]); acc[13] = fmaf(a, w3.y, acc[13]);
        acc[14] = fmaf(a, w3.z, acc[14]); acc[15] = fmaf(a, w3.w, acc[15]);
    }

    const long orow = row0 + lane;
    if (orow < N_NODES) {
        float* o = support + orow * OUT_F + c0;
        *(float4*)(o + 0)  = make_float4(acc[0],  acc[1],  acc[2],  acc[3]);
        *(float4*)(o + 4)  = make_float4(acc[4],  acc[5],  acc[6],  acc[7]);
        *(float4*)(o + 8)  = make_float4(acc[8],  acc[9],  acc[10], acc[11]);
        *(float4*)(o + 12) = make_float4(acc[12], acc[13], acc[14], acc[15]);
    }
}

// ===========================================================================
__global__ __launch_bounds__(256) void zero_kernel(int* __restrict__ p, int n)
{
    int i = blockIdx.x * 256 + threadIdx.x;
    if (i < n) p[i] = 0;
}

// ===========================================================================
// B1: per-bucket edge counts (LDS-aggregated histogram -> global add)
// ===========================================================================
__global__ __launch_bounds__(256) void count_kernel(
    const int* __restrict__ rows, int* __restrict__ cnt, int nE)
{
    __shared__ int hist[NB];
    const int t = threadIdx.x;
    for (int i = t; i < NB; i += 256) hist[i] = 0;
    __syncthreads();

    for (int e = blockIdx.x * 256 + t; e < nE; e += gridDim.x * 256)
        atomicAdd(&hist[rows[e] >> 6], 1);
    __syncthreads();

    for (int i = t; i < NB; i += 256) {
        int h = hist[i];
        if (h) atomicAdd(&cnt[i], h);
    }
}

// ===========================================================================
// B2: exclusive scan of NB counts (single block, 8 elems/thread).
// base <- scan(cnt), cursor <- same, base[NB] = nE.
// ===========================================================================
__global__ __launch_bounds__(256) void scan_kernel(
    const int* __restrict__ cnt, int* __restrict__ base,
    int* __restrict__ cursor, int nE)
{
    __shared__ int lds[256];
    const int t = threadIdx.x;
    const int i0 = t * 8;
    int c[8];
    int tot = 0;
    #pragma unroll
    for (int k = 0; k < 8; ++k) {
        c[k] = (i0 + k < NB) ? cnt[i0 + k] : 0;
        tot += c[k];
    }

    lds[t] = tot;
    __syncthreads();
    int sum = tot;
    #pragma unroll
    for (int off = 1; off < 256; off <<= 1) {
        int y = (t >= off) ? lds[t - off] : 0;
        __syncthreads();
        sum += y;
        lds[t] = sum;
        __syncthreads();
    }
    int run = sum - tot;   // exclusive prefix for i0

    #pragma unroll
    for (int k = 0; k < 8; ++k) {
        if (i0 + k < NB) { base[i0 + k] = run; cursor[i0 + k] = run; }
        run += c[k];
    }
    if (t == 0) base[NB] = nE;
}

// ===========================================================================
// B3: bin edges into bucket-grouped array. LDS hist -> local rank; one
// cursor atomic per (tile,bucket); writes cluster at NB live fronts.
// payload: x = (row&63)<<17 | col (col < 2^17), y = bits of val.
// ===========================================================================
__global__ __launch_bounds__(256) void bin_kernel(
    const int* __restrict__ rows, const int* __restrict__ cols,
    const float* __restrict__ vals, int* __restrict__ cursor,
    uint2* __restrict__ binned, int nE)
{
    __shared__ int hist[NB];
    __shared__ int lbase[NB];
    const int t  = threadIdx.x;
    const int tb = blockIdx.x * BIN_TILE;

    for (int i = t; i < NB; i += 256) hist[i] = 0;
    __syncthreads();

    int myr[8], myrank[8];
    #pragma unroll
    for (int i = 0; i < 8; ++i) {
        int e = tb + i * 256 + t;
        if (e < nE) {
            int r = rows[e];
            myr[i] = r;
            myrank[i] = atomicAdd(&hist[r >> 6], 1);
        } else myr[i] = -1;
    }
    __syncthreads();

    for (int i = t; i < NB; i += 256) {
        int h = hist[i];
        lbase[i] = h ? atomicAdd(&cursor[i], h) : 0;
    }
    __syncthreads();

    #pragma unroll
    for (int i = 0; i < 8; ++i) {
        int e = tb + i * 256 + t;
        if (e < nE) {
            int r = myr[i];
            unsigned pack = ((unsigned)(r & (BROWS - 1)) << 17) | (unsigned)cols[e];
            binned[lbase[r >> 6] + myrank[i]] =
                make_uint2(pack, __float_as_uint(vals[e]));
        }
    }
}

// ===========================================================================
// B4: per-bucket accumulate. 512 thr (8 waves) per block, one block per
// bucket, acc[64][64] = 16 KB LDS -> 4 blocks/CU = 32 waves/CU (full occ).
// Per CU in flight: 32 waves x 8 gathers x 256B = 64 KB -> latency covered.
// ===========================================================================
__global__ __launch_bounds__(512, 8) void bucket_spmm(
    const int* __restrict__ base, const uint2* __restrict__ binned,
    const float* __restrict__ support, const float* __restrict__ bias,
    float* __restrict__ out)
{
    __shared__ float acc[BROWS * OUT_F];   // 16 KB
    const int t = threadIdx.x;
    float4* acc4 = (float4*)acc;
    acc4[t]       = make_float4(0.f, 0.f, 0.f, 0.f);
    acc4[t + 512] = make_float4(0.f, 0.f, 0.f, 0.f);
    __syncthreads();

    const int b = blockIdx.x;
    const int s = base[b];
    const int e = base[b + 1];
    const int wid  = __builtin_amdgcn_readfirstlane(t >> 6);   // 0..7
    const int lane = t & 63;

    for (int j = s + wid * UN; j < e; j += 8 * UN) {
        float g[UN], v[UN];
        int rl[UN];
        #pragma unroll
        for (int k = 0; k < UN; ++k) {
            int idx = j + k;
            uint2 p = (idx < e) ? binned[idx] : make_uint2(0u, 0u);
            int col = (int)(p.x & 131071u);
            rl[k] = (int)(p.x >> 17);
            v[k]  = __uint_as_float(p.y);
            g[k]  = support[(long)col * OUT_F + lane];
        }
        #pragma unroll
        for (int k = 0; k < UN; ++k)
            atomicAdd(&acc[rl[k] * OUT_F + lane], v[k] * g[k]);
    }
    __syncthreads();

    // epilogue: out[bucket rows] = acc + bias (coalesced float4)
    const int row0  = b * BROWS;
    const int nrows = min(BROWS, N_NODES - row0);
    const int nf4   = nrows * 16;
    const float4 bb = ((const float4*)bias)[t & 15];
    float4* out4 = (float4*)(out + (long)row0 * OUT_F);
    for (int i = t; i < nf4; i += 512) {
        float4 a = acc4[i];
        out4[i] = make_float4(a.x + bb.x, a.y + bb.y, a.z + bb.z, a.w + bb.w);
    }
}

// ===========================================================================
// Fallback path (ws too small): bias-init + atomic scatter
// ===========================================================================
__global__ __launch_bounds__(256) void bias_init_kernel(
    float* __restrict__ out, const float* __restrict__ bias, int total4)
{
    const float4* b4 = (const float4*)bias;
    float4* o4 = (float4*)out;
    int i = blockIdx.x * blockDim.x + threadIdx.x;
    int stride = gridDim.x * blockDim.x;
    for (; i < total4; i += stride)
        o4[i] = b4[i & 15];
}

__global__ __launch_bounds__(256) void scatter_kernel(
    const float* __restrict__ vals, const int* __restrict__ rows,
    const int* __restrict__ cols, const float* __restrict__ support,
    float* __restrict__ out, int nE)
{
    const int e = blockIdx.x * 4 + (threadIdx.x >> 6);
    if (e >= nE) return;
    const int f = threadIdx.x & 63;
    const float m = vals[e] * support[(long)cols[e] * OUT_F + f];
    atomicAdd(&out[(long)rows[e] * OUT_F + f], m);
}

// ===========================================================================
extern "C" void kernel_launch(void* const* d_in, const int* in_sizes, int n_in,
                              void* d_out, int out_size, void* d_ws, size_t ws_size,
                              hipStream_t stream) {
    const float* input    = (const float*)d_in[0];
    const float* weights  = (const float*)d_in[1];
    const float* bias     = (const float*)d_in[2];
    const float* adj_vals = (const float*)d_in[3];
    const int*   adj_rows = (const int*)d_in[4];
    const int*   adj_cols = (const int*)d_in[5];
    const int nE = in_sizes[3];

    float* out = (float*)d_out;

    // workspace layout (16B-aligned offsets)
    char* ws = (char*)d_ws;
    const size_t off_support = 0;                      // N*64 floats = 25.6 MB
    const size_t off_base    = 25600000;               // (NB+1) ints
    const size_t off_cursor  = off_base + 6400;        // NB ints
    const size_t off_binned  = off_cursor + 6400;      // nE uint2
    const size_t required    = off_binned + (size_t)nE * 8;

    float* support = (float*)(ws + off_support);
    int*   bbase   = (int*)  (ws + off_base);
    int*   cursor  = (int*)  (ws + off_cursor);
    uint2* binned  = (uint2*)(ws + off_binned);

    // 1) support = input @ W
    hipLaunchKernelGGL(gemm_kernel, dim3((N_NODES + 63) / 64), dim3(256), 0,
                       stream, input, weights, support);

    if (ws_size >= required) {
        // 2) cursor (as counts) = 0
        hipLaunchKernelGGL(zero_kernel, dim3((NB + 255) / 256), dim3(256),
                           0, stream, cursor, NB);
        // 3) per-bucket counts
        hipLaunchKernelGGL(count_kernel, dim3(256), dim3(256), 0, stream,
                           adj_rows, cursor, nE);
        // 4) scan -> base, cursor
        hipLaunchKernelGGL(scan_kernel, dim3(1), dim3(256), 0, stream,
                           cursor, bbase, cursor, nE);
        // 5) bin edges by bucket
        hipLaunchKernelGGL(bin_kernel, dim3((nE + BIN_TILE - 1) / BIN_TILE),
                           dim3(256), 0, stream,
                           adj_rows, adj_cols, adj_vals, cursor, binned, nE);
        // 6) per-bucket LDS accumulate + bias -> out
        hipLaunchKernelGGL(bucket_spmm, dim3(NB), dim3(512), 0, stream,
                           bbase, binned, support, bias, out);
    } else {
        hipLaunchKernelGGL(bias_init_kernel, dim3(2048), dim3(256), 0, stream,
                           out, bias, N_NODES * OUT_F / 4);
        hipLaunchKernelGGL(scatter_kernel, dim3((nE + 3) / 4), dim3(256),
                           0, stream, adj_vals, adj_rows, adj_cols, support,
                           out, nE);
    }
}